// Round 9
// baseline (220.511 us; speedup 1.0000x reference)
//
#include <hip/hip_runtime.h>
#include <hip/hip_bf16.h>

typedef __bf16 bf16_t;
typedef __bf16 bf16x8 __attribute__((ext_vector_type(8)));
typedef float  f32x4  __attribute__((ext_vector_type(4)));
typedef unsigned int u32x4 __attribute__((ext_vector_type(4)));

#define DDIM 1024
#define NTOK 1024
#define MATN (1024 * 1024)
#define BK 64

// raw barrier / partial vm-wait: __syncthreads would emit s_waitcnt vmcnt(0)
// and drain the prefetch (the m97 ~20% stall).
#define BAR()   asm volatile("s_barrier" ::: "memory")
#define WVM(n)  asm volatile("s_waitcnt vmcnt(" #n ")" ::: "memory")

__device__ __forceinline__ void load16(const bf16_t* g, bf16_t* l) {
  __builtin_amdgcn_global_load_lds(
      (__attribute__((address_space(1))) void*)(g),
      (__attribute__((address_space(3))) void*)(l), 16, 0, 0);
}

// swizzled fragment offset: elem (row, k-group g=kk/8) lives at
// row*64 + ((g ^ (row&7))*8)   [gather side permuted to match]
__device__ __forceinline__ int sw_off(int row, int kk) {
  return row * BK + (((kk >> 3) ^ (row & 7)) << 3);
}

// ---------------- prep: x->bf16, zero out/list/wrow, FUSED router ----------------
// 512 blocks x 256 threads; each block covers 2 tokens.
__global__ void prep_k(const float* __restrict__ x, bf16_t* __restrict__ xb,
                       float* __restrict__ out, int* __restrict__ list,
                       float* __restrict__ wrow,
                       const float* __restrict__ rw, const float* __restrict__ bias,
                       int* __restrict__ tsel, float* __restrict__ tscore) {
  __shared__ float red[4][8];
  const int tid = threadIdx.x;
  const int i = blockIdx.x * 256 + tid;
  const int j = i * 8;
  const f32x4 a = *(const f32x4*)(x + j);
  const f32x4 b = *(const f32x4*)(x + j + 4);
  bf16x8 v;
#pragma unroll
  for (int t = 0; t < 4; ++t) { v[t] = (bf16_t)a[t]; v[t + 4] = (bf16_t)b[t]; }
  *(bf16x8*)(xb + j) = v;
  const f32x4 z = {0.f, 0.f, 0.f, 0.f};
  *(f32x4*)(out + j) = z; *(f32x4*)(out + j + 4) = z;
  if (i < 4096) { list[i] = 0; wrow[i] = 0.f; }

  const int dbase = (tid & 127) * 8;
  float acc[8];
#pragma unroll
  for (int e = 0; e < 8; ++e) acc[e] = 0.f;
#pragma unroll
  for (int t = 0; t < 8; ++t) {
    const float xv = (t < 4) ? a[t] : b[t - 4];
    const f32x4 w0 = *(const f32x4*)(rw + (dbase + t) * 8);
    const f32x4 w1 = *(const f32x4*)(rw + (dbase + t) * 8 + 4);
#pragma unroll
    for (int e = 0; e < 4; ++e) { acc[e] += xv * w0[e]; acc[e + 4] += xv * w1[e]; }
  }
#pragma unroll
  for (int off = 32; off >= 1; off >>= 1)
#pragma unroll
    for (int e = 0; e < 8; ++e) acc[e] += __shfl_xor(acc[e], off, 64);
  const int lane = tid & 63, wave = tid >> 6;
  if (lane == 0) {
#pragma unroll
    for (int e = 0; e < 8; ++e) red[wave][e] = acc[e];
  }
  __syncthreads();
  if ((tid & 127) == 0) {                   // threads 0 and 128
    const int n = blockIdx.x * 2 + (tid >> 7);
    float lg[8];
#pragma unroll
    for (int e = 0; e < 8; ++e) lg[e] = red[wave][e] + red[wave + 1][e];
    float mx = lg[0];
#pragma unroll
    for (int e = 1; e < 8; ++e) mx = fmaxf(mx, lg[e]);
    float p[8], s = 0.f;
#pragma unroll
    for (int e = 0; e < 8; ++e) { p[e] = __expf(lg[e] - mx); s += p[e]; }
    const float inv = 1.f / s;
    float sc[8], sb2[8];
#pragma unroll
    for (int e = 0; e < 8; ++e) { sc[e] = p[e] * inv; sb2[e] = sc[e] + bias[e]; }
    int i1 = 0;
#pragma unroll
    for (int e = 1; e < 8; ++e) if (sb2[e] > sb2[i1]) i1 = e;   // ties -> lowest idx
    int i2 = (i1 == 0) ? 1 : 0;
#pragma unroll
    for (int e = 0; e < 8; ++e) if (e != i2 && e != i1 && sb2[e] > sb2[i2]) i2 = e;
    tsel[n * 2 + 0] = i1; tscore[n * 2 + 0] = sc[i1];
    tsel[n * 2 + 1] = i2; tscore[n * 2 + 1] = sc[i2];
  }
}

// ---------------- pack: LDS-atomic positions + scan + fill, one dispatch ----------------
// 128-row tiles. max routed base <= 2944, + 1024 shared <= 3968 < 4096.
__global__ void pack_k(const int* __restrict__ tsel, const float* __restrict__ tscore,
                       int* __restrict__ ntp, int* __restrict__ tile_e,
                       int* __restrict__ tile_m0, int* __restrict__ list,
                       float* __restrict__ wrow) {
  __shared__ int scnt[8];
  __shared__ int sb[9];
  const int tid = threadIdx.x;          // 1024 threads = 1 per token
  if (tid < 8) scnt[tid] = 0;
  __syncthreads();
  const int e0 = tsel[tid * 2 + 0];
  const int p0 = atomicAdd(&scnt[e0], 1);
  const int e1 = tsel[tid * 2 + 1];
  const int p1 = atomicAdd(&scnt[e1], 1);
  __syncthreads();
  if (tid == 0) {
    int pt = 0, base = 0;
    for (int e = 0; e < 8; ++e) {
      sb[e] = base;
      const int nt = (scnt[e] + 127) >> 7;
      for (int jj = 0; jj < nt; ++jj) { tile_e[pt] = e; tile_m0[pt] = base + jj * 128; ++pt; }
      base += nt << 7;
    }
    sb[8] = base;
    for (int jj = 0; jj < 8; ++jj) { tile_e[pt] = 8; tile_m0[pt] = base + jj * 128; ++pt; }
    ntp[0] = pt;                        // <= 31
  }
  __syncthreads();
  const int s0 = sb[e0] + p0; list[s0] = tid; wrow[s0] = tscore[tid * 2 + 0];
  const int s1 = sb[e1] + p1; list[s1] = tid; wrow[s1] = tscore[tid * 2 + 1];
  const int ss = sb[8] + tid; list[ss] = tid; wrow[ss] = 1.f;
}

// ---------------- weight transpose+convert, 128x128 f32 tiles ----------------
// grid (8, 8, 9*kinds), 256 threads. Chunk-size experiment: 512 B contiguous
// reads per source row, 256 B contiguous writes per dest row (2x the 64x64
// version, which is pattern-capped at ~2.5 TB/s; pipelining proved neutral).
// LDS: u32-packed bf16 pairs, [128][65] pad (reads 2-way = free; write 4-way
// conflict accepted - LDS is nowhere near critical path here).
__global__ void transpose3_k(const float* __restrict__ a8, const float* __restrict__ aS,
                             bf16_t* __restrict__ da,
                             const float* __restrict__ b8, const float* __restrict__ bS,
                             bf16_t* __restrict__ db,
                             const float* __restrict__ c8, const float* __restrict__ cS,
                             bf16_t* __restrict__ dc) {
  const int z = blockIdx.z, kind = z / 9, e = z % 9;
  const float* src;
  bf16_t* dst;
  if (kind == 0)      { src = (e < 8) ? a8 + (size_t)e * MATN : aS; dst = da + (size_t)e * MATN; }
  else if (kind == 1) { src = (e < 8) ? b8 + (size_t)e * MATN : bS; dst = db + (size_t)e * MATN; }
  else                { src = (e < 8) ? c8 + (size_t)e * MATN : cS; dst = dc + (size_t)e * MATN; }

  __shared__ unsigned int T[128][65];
  const int t = threadIdx.x;
  const int n0 = blockIdx.x * 128;   // dest-row / source-col panel
  const int k0 = blockIdx.y * 128;   // source-row / dest-col panel

  // load: thread handles source rows k0+2p, k0+2p+1; cols n0+cg*32 .. +31
  const int p = t >> 2, cg = t & 3;
  {
    const float* s0 = src + (size_t)(k0 + 2 * p) * DDIM + n0 + cg * 32;
    f32x4 A[8], B[8];
#pragma unroll
    for (int c = 0; c < 8; ++c) { A[c] = *(const f32x4*)(s0 + c * 4); }
#pragma unroll
    for (int c = 0; c < 8; ++c) { B[c] = *(const f32x4*)(s0 + DDIM + c * 4); }
#pragma unroll
    for (int c = 0; c < 8; ++c)
#pragma unroll
      for (int i = 0; i < 4; ++i) {
        union { bf16_t h[2]; unsigned int u; } pk;
        pk.h[0] = (bf16_t)A[c][i];   // k = k0+2p
        pk.h[1] = (bf16_t)B[c][i];   // k = k0+2p+1
        T[cg * 32 + c * 4 + i][p] = pk.u;
      }
  }
  __syncthreads();
  // store: thread writes dest row n0+r, k-cols k0 + h*64 .. +63 (128 B contig)
  {
    const int r = t >> 1, h = t & 1;
    bf16_t* dp = dst + (size_t)(n0 + r) * DDIM + k0 + h * 64;
#pragma unroll
    for (int q = 0; q < 8; ++q) {
      const unsigned int w0 = T[r][h * 32 + q * 4 + 0];
      const unsigned int w1 = T[r][h * 32 + q * 4 + 1];
      const unsigned int w2 = T[r][h * 32 + q * 4 + 2];
      const unsigned int w3 = T[r][h * 32 + q * 4 + 3];
      const u32x4 vv = { w0, w1, w2, w3 };
      *(u32x4*)(dp + q * 8) = vv;
    }
  }
}

// ---------------- fused dual-B GEMM: G = silu(X W1^T) * (X W3^T) ----------------
// 128x64 tile (M=128), double-buffered LDS, raw-barrier pipeline, swizzled layout.
// LDS = 32+16+16 = 64 KB -> 2 blocks/CU.  [measured-best structure, 209 us total]
__global__ __launch_bounds__(256, 2)
void gemm12_k(const bf16_t* __restrict__ xb, const bf16_t* __restrict__ wt1,
              const bf16_t* __restrict__ wt3, bf16_t* __restrict__ G,
              const int* __restrict__ tile_e, const int* __restrict__ tile_m0,
              const int* __restrict__ ntp, const int* __restrict__ list) {
  const int ti = blockIdx.y;
  if (ti >= ntp[0]) return;
  const int e = tile_e[ti], slot0 = tile_m0[ti];
  const int n0 = blockIdx.x * 64;

  __shared__ __align__(16) bf16_t sA[2][128 * BK];
  __shared__ __align__(16) bf16_t sB1[2][64 * BK];
  __shared__ __align__(16) bf16_t sB3[2][64 * BK];

  const int lane = threadIdx.x & 63, wave = threadIdx.x >> 6;
  const int wm = wave & 1, wn = wave >> 1;
  const int srr = lane >> 3;
  const int scol = ((lane & 7) ^ srr) * 8;   // swizzled gather column

  const bf16_t *aS[4], *b1S[2], *b3S[2];
#pragma unroll
  for (int i = 0; i < 4; ++i) {
    const int c = wave * 4 + i;              // A chunk 0..15 (8 rows each)
    const int r = c * 8 + srr;               // row 0..127
    aS[i] = xb + (size_t)list[slot0 + r] * DDIM + scol;
  }
#pragma unroll
  for (int i = 0; i < 2; ++i) {
    const int c = wave * 2 + i;              // B chunk 0..7
    const int r = c * 8 + srr;
    const size_t wb = (size_t)e * MATN + (size_t)(n0 + r) * DDIM + scol;
    b1S[i] = wt1 + wb; b3S[i] = wt3 + wb;
  }

  const f32x4 z = {0.f, 0.f, 0.f, 0.f};
  f32x4 aU[4][2], aV[4][2];
#pragma unroll
  for (int a = 0; a < 4; ++a)
#pragma unroll
    for (int b = 0; b < 2; ++b) { aU[a][b] = z; aV[a][b] = z; }

#define ISSUE12(j, b)                                            \
  _Pragma("unroll") for (int i = 0; i < 4; ++i)                  \
    load16(aS[i] + (j) * BK, &sA[b][(wave * 4 + i) * 512]);      \
  _Pragma("unroll") for (int i = 0; i < 2; ++i) {                \
    load16(b1S[i] + (j) * BK, &sB1[b][(wave * 2 + i) * 512]);    \
    load16(b3S[i] + (j) * BK, &sB3[b][(wave * 2 + i) * 512]);    \
  }

#define COMPUTE12(b)                                                          \
  _Pragma("unroll") for (int ks = 0; ks < 2; ++ks) {                          \
    const int kk = ks * 32 + ((lane >> 4) * 8);                               \
    bf16x8 af[4], f1[2], f3[2];                                               \
    _Pragma("unroll") for (int mf = 0; mf < 4; ++mf)                          \
      af[mf] = *(const bf16x8*)&sA[b][sw_off(wm * 64 + mf * 16 + (lane & 15), kk)]; \
    _Pragma("unroll") for (int nf = 0; nf < 2; ++nf) {                        \
      const int ro = sw_off(wn * 32 + nf * 16 + (lane & 15), kk);             \
      f1[nf] = *(const bf16x8*)&sB1[b][ro];                                   \
      f3[nf] = *(const bf16x8*)&sB3[b][ro];                                   \
    }                                                                         \
    _Pragma("unroll") for (int nf = 0; nf < 2; ++nf)                          \
      _Pragma("unroll") for (int mf = 0; mf < 4; ++mf) {                      \
        aU[mf][nf] = __builtin_amdgcn_mfma_f32_16x16x32_bf16(af[mf], f1[nf], aU[mf][nf], 0, 0, 0); \
        aV[mf][nf] = __builtin_amdgcn_mfma_f32_16x16x32_bf16(af[mf], f3[nf], aV[mf][nf], 0, 0, 0); \
      }                                                                       \
  }

  ISSUE12(0, 0);
#pragma unroll
  for (int j = 0; j < 15; ++j) {
    ISSUE12(j + 1, (j + 1) & 1);
    WVM(8); BAR();
    COMPUTE12(j & 1);
    BAR();
  }
  WVM(0); BAR();
  COMPUTE12(1);

  // epilogue: G = silu(U)*V.  C/D: col=lane&15, row=quad*4+reg (m89/m91)
  const int colb = n0 + wn * 32 + (lane & 15);
#pragma unroll
  for (int mf = 0; mf < 4; ++mf)
#pragma unroll
    for (int rg = 0; rg < 4; ++rg) {
      const int row = wm * 64 + mf * 16 + ((lane >> 4) * 4) + rg;
      bf16_t* gp = G + (size_t)(slot0 + row) * DDIM + colb;
#pragma unroll
      for (int nf = 0; nf < 2; ++nf) {
        const float u = aU[mf][nf][rg];
        gp[nf * 16] = (bf16_t)((u / (1.f + __expf(-u))) * aV[mf][nf][rg]);
      }
    }
#undef ISSUE12
#undef COMPUTE12
}

// ---------------- single-B GEMM (dbuf+swizzle, M=128). MODE: 0=U 1=V+SwiGLU 2=out ----------------
// LDS = 32+16 = 48 KB -> 3 blocks/CU.
template <int MODE>
__global__ __launch_bounds__(256, 3)
void gemmS_k(const bf16_t* __restrict__ Asrc, const bf16_t* __restrict__ wt,
             bf16_t* __restrict__ UG, float* __restrict__ oacc,
             const int* __restrict__ tile_e, const int* __restrict__ tile_m0,
             const int* __restrict__ ntp, const int* __restrict__ list,
             const float* __restrict__ wrow) {
  const int ti = blockIdx.y;
  if (ti >= ntp[0]) return;
  const int e = tile_e[ti], slot0 = tile_m0[ti];
  const int n0 = blockIdx.x * 64;

  __shared__ __align__(16) bf16_t sA[2][128 * BK];
  __shared__ __align__(16) bf16_t sB[2][64 * BK];

  const int lane = threadIdx.x & 63, wave = threadIdx.x >> 6;
  const int wm = wave & 1, wn = wave >> 1;
  const int srr = lane >> 3;
  const int scol = ((lane & 7) ^ srr) * 8;

  const bf16_t *aS[4], *bS[2];
#pragma unroll
  for (int i = 0; i < 4; ++i) {
    const int c = wave * 4 + i;
    const int r = c * 8 + srr;
    const int slot = slot0 + r;
    aS[i] = Asrc + (size_t)((MODE == 2) ? slot : list[slot]) * DDIM + scol;
  }
#pragma unroll
  for (int i = 0; i < 2; ++i) {
    const int c = wave * 2 + i;
    const int r = c * 8 + srr;
    bS[i] = wt + (size_t)e * MATN + (size_t)(n0 + r) * DDIM + scol;
  }

  const f32x4 z = {0.f, 0.f, 0.f, 0.f};
  f32x4 acc[4][2];
#pragma unroll
  for (int a = 0; a < 4; ++a)
#pragma unroll
    for (int b = 0; b < 2; ++b) acc[a][b] = z;

#define ISSUES(j, b)                                           \
  _Pragma("unroll") for (int i = 0; i < 4; ++i)                \
    load16(aS[i] + (j) * BK, &sA[b][(wave * 4 + i) * 512]);    \
  _Pragma("unroll") for (int i = 0; i < 2; ++i)                \
    load16(bS[i] + (j) * BK, &sB[b][(wave * 2 + i) * 512]);

#define COMPUTES(b)                                                           \
  _Pragma("unroll") for (int ks = 0; ks < 2; ++ks) {                          \
    const int kk = ks * 32 + ((lane >> 4) * 8);                               \
    bf16x8 af[4], fb[2];                                                      \
    _Pragma("unroll") for (int mf = 0; mf < 4; ++mf)                          \
      af[mf] = *(const bf16x8*)&sA[b][sw_off(wm * 64 + mf * 16 + (lane & 15), kk)]; \
    _Pragma("unroll") for (int nf = 0; nf < 2; ++nf)                          \
      fb[nf] = *(const bf16x8*)&sB[b][sw_off(wn * 32 + nf * 16 + (lane & 15), kk)]; \
    _Pragma("unroll") for (int nf = 0; nf < 2; ++nf)                          \
      _Pragma("unroll") for (int mf = 0; mf < 4; ++mf)                        \
        acc[mf][nf] = __builtin_amdgcn_mfma_f32_16x16x32_bf16(af[mf], fb[nf], acc[mf][nf], 0, 0, 0); \
  }

  ISSUES(0, 0);
#pragma unroll
  for (int j = 0; j < 15; ++j) {
    ISSUES(j + 1, (j + 1) & 1);
    WVM(6); BAR();
    COMPUTES(j & 1);
    BAR();
  }
  WVM(0); BAR();
  COMPUTES(1);

  const int colb = n0 + wn * 32 + (lane & 15);
#pragma unroll
  for (int mf = 0; mf < 4; ++mf)
#pragma unroll
    for (int rg = 0; rg < 4; ++rg) {
      const int row = wm * 64 + mf * 16 + ((lane >> 4) * 4) + rg;
      const int slot = slot0 + row;
      if (MODE == 0) {
        bf16_t* gp = UG + (size_t)slot * DDIM + colb;
#pragma unroll
        for (int nf = 0; nf < 2; ++nf) gp[nf * 16] = (bf16_t)acc[mf][nf][rg];
      } else if (MODE == 1) {
        bf16_t* gp = UG + (size_t)slot * DDIM + colb;
#pragma unroll
        for (int nf = 0; nf < 2; ++nf) {
          const float u = (float)gp[nf * 16];
          gp[nf * 16] = (bf16_t)((u / (1.f + __expf(-u))) * acc[mf][nf][rg]);
        }
      } else {
        const float w = wrow[slot];
        if (w != 0.f) {
          float* dst = oacc + (size_t)list[slot] * DDIM + colb;
#pragma unroll
          for (int nf = 0; nf < 2; ++nf)
            atomicAdd(dst + nf * 16, w * acc[mf][nf][rg]);
        }
      }
    }
#undef ISSUES
#undef COMPUTES
}

extern "C" void kernel_launch(void* const* d_in, const int* in_sizes, int n_in,
                              void* d_out, int out_size, void* d_ws, size_t ws_size,
                              hipStream_t stream) {
  (void)in_sizes; (void)n_in; (void)out_size;
  const float* x   = (const float*)d_in[0];
  const float* rw  = (const float*)d_in[1];
  const float* eb  = (const float*)d_in[2];
  const float* w1  = (const float*)d_in[3];
  const float* w2  = (const float*)d_in[4];
  const float* w3  = (const float*)d_in[5];
  const float* sw1 = (const float*)d_in[6];
  const float* sw2 = (const float*)d_in[7];
  const float* sw3 = (const float*)d_in[8];
  float* out = (float*)d_out;

  char* ws = (char*)d_ws;
  const size_t WT  = 18874368;   // 9 * 2 MiB bf16
  const size_t XBS = 2097152, GS = 8388608, MS = 65536;
  const int mode = (ws_size >= 3 * WT + XBS + GS + MS) ? 3
                 : (ws_size >= 2 * WT + XBS + GS + MS) ? 2 : 1;

  size_t off = 0;
  bf16_t* wtA = (bf16_t*)(ws); off += WT;
  bf16_t* wtB = wtA; bf16_t* wtC = wtA;
  if (mode >= 2) { wtB = (bf16_t*)(ws + off); off += WT; }
  if (mode == 3) { wtC = (bf16_t*)(ws + off); off += WT; }
  bf16_t* xb = (bf16_t*)(ws + off); off += XBS;
  bf16_t* G  = (bf16_t*)(ws + off); off += GS;
  int* meta  = (int*)(ws + off);

  int*   ntp     = meta + 32;
  int*   tile_e  = meta + 40;
  int*   tile_m0 = meta + 104;
  int*   tsel    = meta + 168;
  int*   list    = meta + 4264;
  float* tscore  = (float*)(meta + 8360);
  float* wrow    = (float*)(meta + 10408);

  prep_k<<<512, 256, 0, stream>>>(x, xb, out, list, wrow, rw, eb, tsel, tscore);
  pack_k<<<1, 1024, 0, stream>>>(tsel, tscore, ntp, tile_e, tile_m0, list, wrow);

  if (mode == 3) {
    // all 27 weight transposes in one dispatch; no serial transpose between GEMMs
    transpose3_k<<<dim3(8, 8, 27), 256, 0, stream>>>(w1, sw1, wtA, w3, sw3, wtB, w2, sw2, wtC);
    gemm12_k<<<dim3(16, 31), 256, 0, stream>>>(xb, wtA, wtB, G, tile_e, tile_m0, ntp, list);
    gemmS_k<2><<<dim3(16, 31), 256, 0, stream>>>(G, wtC, G, out, tile_e, tile_m0, ntp, list, wrow);
  } else if (mode == 2) {
    transpose3_k<<<dim3(8, 8, 18), 256, 0, stream>>>(w1, sw1, wtA, w3, sw3, wtB, w3, sw3, wtB);
    gemm12_k<<<dim3(16, 31), 256, 0, stream>>>(xb, wtA, wtB, G, tile_e, tile_m0, ntp, list);
    transpose3_k<<<dim3(8, 8, 9), 256, 0, stream>>>(w2, sw2, wtA, w2, sw2, wtA, w2, sw2, wtA);
    gemmS_k<2><<<dim3(16, 31), 256, 0, stream>>>(G, wtA, G, out, tile_e, tile_m0, ntp, list, wrow);
  } else {
    transpose3_k<<<dim3(8, 8, 9), 256, 0, stream>>>(w1, sw1, wtA, w1, sw1, wtA, w1, sw1, wtA);
    gemmS_k<0><<<dim3(16, 31), 256, 0, stream>>>(xb, wtA, G, out, tile_e, tile_m0, ntp, list, wrow);
    transpose3_k<<<dim3(8, 8, 9), 256, 0, stream>>>(w3, sw3, wtA, w3, sw3, wtA, w3, sw3, wtA);
    gemmS_k<1><<<dim3(16, 31), 256, 0, stream>>>(xb, wtA, G, out, tile_e, tile_m0, ntp, list, wrow);
    transpose3_k<<<dim3(8, 8, 9), 256, 0, stream>>>(w2, sw2, wtA, w2, sw2, wtA, w2, sw2, wtA);
    gemmS_k<2><<<dim3(16, 31), 256, 0, stream>>>(G, wtA, G, out, tile_e, tile_m0, ntp, list, wrow);
  }
}

// Round 14
// 207.581 us; speedup vs baseline: 1.0623x; 1.0623x over previous
//
#include <hip/hip_runtime.h>
#include <hip/hip_bf16.h>

typedef __bf16 bf16_t;
typedef __bf16 bf16x8 __attribute__((ext_vector_type(8)));
typedef float  f32x4  __attribute__((ext_vector_type(4)));
typedef unsigned int u32x4 __attribute__((ext_vector_type(4)));

#define DDIM 1024
#define NTOK 1024
#define MATN (1024 * 1024)
#define BK 64

// raw barrier / partial vm-wait: __syncthreads would emit s_waitcnt vmcnt(0)
// and drain the prefetch (the m97 ~20% stall).
#define BAR()   asm volatile("s_barrier" ::: "memory")
#define WVM(n)  asm volatile("s_waitcnt vmcnt(" #n ")" ::: "memory")

__device__ __forceinline__ void load16(const bf16_t* g, bf16_t* l) {
  __builtin_amdgcn_global_load_lds(
      (__attribute__((address_space(1))) void*)(g),
      (__attribute__((address_space(3))) void*)(l), 16, 0, 0);
}

// swizzled fragment offset: elem (row, k-group g=kk/8) lives at
// row*64 + ((g ^ (row&7))*8)   [gather side permuted to match]
__device__ __forceinline__ int sw_off(int row, int kk) {
  return row * BK + (((kk >> 3) ^ (row & 7)) << 3);
}

// ---------------- prep: x->bf16, zero out/list/wrow, FUSED router ----------------
// 512 blocks x 256 threads; each block covers 2 tokens.
__global__ void prep_k(const float* __restrict__ x, bf16_t* __restrict__ xb,
                       float* __restrict__ out, int* __restrict__ list,
                       float* __restrict__ wrow,
                       const float* __restrict__ rw, const float* __restrict__ bias,
                       int* __restrict__ tsel, float* __restrict__ tscore) {
  __shared__ float red[4][8];
  const int tid = threadIdx.x;
  const int i = blockIdx.x * 256 + tid;
  const int j = i * 8;
  const f32x4 a = *(const f32x4*)(x + j);
  const f32x4 b = *(const f32x4*)(x + j + 4);
  bf16x8 v;
#pragma unroll
  for (int t = 0; t < 4; ++t) { v[t] = (bf16_t)a[t]; v[t + 4] = (bf16_t)b[t]; }
  *(bf16x8*)(xb + j) = v;
  const f32x4 z = {0.f, 0.f, 0.f, 0.f};
  *(f32x4*)(out + j) = z; *(f32x4*)(out + j + 4) = z;
  if (i < 4096) { list[i] = 0; wrow[i] = 0.f; }

  const int dbase = (tid & 127) * 8;
  float acc[8];
#pragma unroll
  for (int e = 0; e < 8; ++e) acc[e] = 0.f;
#pragma unroll
  for (int t = 0; t < 8; ++t) {
    const float xv = (t < 4) ? a[t] : b[t - 4];
    const f32x4 w0 = *(const f32x4*)(rw + (dbase + t) * 8);
    const f32x4 w1 = *(const f32x4*)(rw + (dbase + t) * 8 + 4);
#pragma unroll
    for (int e = 0; e < 4; ++e) { acc[e] += xv * w0[e]; acc[e + 4] += xv * w1[e]; }
  }
#pragma unroll
  for (int off = 32; off >= 1; off >>= 1)
#pragma unroll
    for (int e = 0; e < 8; ++e) acc[e] += __shfl_xor(acc[e], off, 64);
  const int lane = tid & 63, wave = tid >> 6;
  if (lane == 0) {
#pragma unroll
    for (int e = 0; e < 8; ++e) red[wave][e] = acc[e];
  }
  __syncthreads();
  if ((tid & 127) == 0) {                   // threads 0 and 128
    const int n = blockIdx.x * 2 + (tid >> 7);
    float lg[8];
#pragma unroll
    for (int e = 0; e < 8; ++e) lg[e] = red[wave][e] + red[wave + 1][e];
    float mx = lg[0];
#pragma unroll
    for (int e = 1; e < 8; ++e) mx = fmaxf(mx, lg[e]);
    float p[8], s = 0.f;
#pragma unroll
    for (int e = 0; e < 8; ++e) { p[e] = __expf(lg[e] - mx); s += p[e]; }
    const float inv = 1.f / s;
    float sc[8], sb2[8];
#pragma unroll
    for (int e = 0; e < 8; ++e) { sc[e] = p[e] * inv; sb2[e] = sc[e] + bias[e]; }
    int i1 = 0;
#pragma unroll
    for (int e = 1; e < 8; ++e) if (sb2[e] > sb2[i1]) i1 = e;   // ties -> lowest idx
    int i2 = (i1 == 0) ? 1 : 0;
#pragma unroll
    for (int e = 0; e < 8; ++e) if (e != i2 && e != i1 && sb2[e] > sb2[i2]) i2 = e;
    tsel[n * 2 + 0] = i1; tscore[n * 2 + 0] = sc[i1];
    tsel[n * 2 + 1] = i2; tscore[n * 2 + 1] = sc[i2];
  }
}

// ---------------- weight transpose+convert (64x64, measured-best) + FUSED pack ----------------
// grid (16, 16, nzt [+1]); z < nzt: transpose; z == nzt: block (0,0) runs pack.
// Transpose is capped ~2.5 TB/s by bytes-in-flight for this f32->bf16 strided
// pattern (one-shot/pipelined/128^2 variants all 45-54 us) — keep the simplest
// measured-best form. Pack rides the same dispatch: stream order guarantees
// prep's tsel is complete; gemm12 waits on this whole dispatch anyway.
__global__ void transpose3_k(const float* __restrict__ a8, const float* __restrict__ aS,
                             bf16_t* __restrict__ da,
                             const float* __restrict__ b8, const float* __restrict__ bS,
                             bf16_t* __restrict__ db,
                             const float* __restrict__ c8, const float* __restrict__ cS,
                             bf16_t* __restrict__ dc, int nzt,
                             const int* __restrict__ tsel, const float* __restrict__ tscore,
                             int* __restrict__ ntp, int* __restrict__ tile_e,
                             int* __restrict__ tile_m0, int* __restrict__ list,
                             float* __restrict__ wrow) {
  const int t = threadIdx.x;

  if ((int)blockIdx.z == nzt) {
    // ---------------- pack slice (one block, 256 threads, 4 tokens/thread) ----------------
    if (blockIdx.x != 0 || blockIdx.y != 0) return;
    __shared__ int scnt[8];
    __shared__ int sb[9];
    if (t < 8) scnt[t] = 0;
    __syncthreads();
    int e4[4][2], p4[4][2];
#pragma unroll
    for (int q = 0; q < 4; ++q) {
      const int n = t * 4 + q;
      e4[q][0] = tsel[n * 2 + 0]; p4[q][0] = atomicAdd(&scnt[e4[q][0]], 1);
      e4[q][1] = tsel[n * 2 + 1]; p4[q][1] = atomicAdd(&scnt[e4[q][1]], 1);
    }
    __syncthreads();
    if (t == 0) {
      int pt = 0, base = 0;
      for (int e = 0; e < 8; ++e) {
        sb[e] = base;
        const int nt = (scnt[e] + 127) >> 7;
        for (int jj = 0; jj < nt; ++jj) { tile_e[pt] = e; tile_m0[pt] = base + jj * 128; ++pt; }
        base += nt << 7;
      }
      sb[8] = base;
      for (int jj = 0; jj < 8; ++jj) { tile_e[pt] = 8; tile_m0[pt] = base + jj * 128; ++pt; }
      ntp[0] = pt;                      // <= 31
    }
    __syncthreads();
#pragma unroll
    for (int q = 0; q < 4; ++q) {
      const int n = t * 4 + q;
      const int s0 = sb[e4[q][0]] + p4[q][0];
      list[s0] = n; wrow[s0] = tscore[n * 2 + 0];
      const int s1 = sb[e4[q][1]] + p4[q][1];
      list[s1] = n; wrow[s1] = tscore[n * 2 + 1];
      const int ss = sb[8] + n;
      list[ss] = n; wrow[ss] = 1.f;
    }
    return;
  }

  // ---------------- transpose path (64x64 tile, one-shot) ----------------
  const int z = blockIdx.z, kind = z / 9, e = z % 9;
  const float* src;
  bf16_t* dst;
  if (kind == 0)      { src = (e < 8) ? a8 + (size_t)e * MATN : aS; dst = da + (size_t)e * MATN; }
  else if (kind == 1) { src = (e < 8) ? b8 + (size_t)e * MATN : bS; dst = db + (size_t)e * MATN; }
  else                { src = (e < 8) ? c8 + (size_t)e * MATN : cS; dst = dc + (size_t)e * MATN; }

  __shared__ unsigned int T[64][33];
  const int k0 = blockIdx.y * 64, n0 = blockIdx.x * 64;
  {
    const int kp = t >> 3, cg = t & 7;
    const float* s0 = src + (size_t)(k0 + 2 * kp) * DDIM + n0 + cg * 8;
    const f32x4 a0 = *(const f32x4*)(s0);
    const f32x4 a1 = *(const f32x4*)(s0 + 4);
    const f32x4 b0 = *(const f32x4*)(s0 + DDIM);
    const f32x4 b1 = *(const f32x4*)(s0 + DDIM + 4);
#pragma unroll
    for (int jj = 0; jj < 4; ++jj) {
      union { bf16_t h[2]; unsigned int u; } p;
      p.h[0] = (bf16_t)a0[jj]; p.h[1] = (bf16_t)b0[jj];
      T[cg * 8 + jj][kp] = p.u;
      p.h[0] = (bf16_t)a1[jj]; p.h[1] = (bf16_t)b1[jj];
      T[cg * 8 + 4 + jj][kp] = p.u;
    }
  }
  __syncthreads();
  {
    const int rn = t >> 2, q = t & 3;
    unsigned int r0[4], r1[4];
#pragma unroll
    for (int i = 0; i < 4; ++i) { r0[i] = T[rn][q * 4 + i]; r1[i] = T[rn][q * 4 + 16 + i]; }
    bf16_t* d = dst + (size_t)(n0 + rn) * DDIM + k0;
    const u32x4 v0 = { r0[0], r0[1], r0[2], r0[3] };
    const u32x4 v1 = { r1[0], r1[1], r1[2], r1[3] };
    *(u32x4*)(d + q * 8) = v0;
    *(u32x4*)(d + q * 8 + 32) = v1;
  }
}

// ---------------- fused dual-B GEMM: G = silu(X W1^T) * (X W3^T) ----------------
// 128x64 tile (M=128), double-buffered LDS, raw-barrier pipeline, swizzled layout.
// LDS = 32+16+16 = 64 KB -> 2 blocks/CU.  [measured-best structure, 209 us total]
__global__ __launch_bounds__(256, 2)
void gemm12_k(const bf16_t* __restrict__ xb, const bf16_t* __restrict__ wt1,
              const bf16_t* __restrict__ wt3, bf16_t* __restrict__ G,
              const int* __restrict__ tile_e, const int* __restrict__ tile_m0,
              const int* __restrict__ ntp, const int* __restrict__ list) {
  const int ti = blockIdx.y;
  if (ti >= ntp[0]) return;
  const int e = tile_e[ti], slot0 = tile_m0[ti];
  const int n0 = blockIdx.x * 64;

  __shared__ __align__(16) bf16_t sA[2][128 * BK];
  __shared__ __align__(16) bf16_t sB1[2][64 * BK];
  __shared__ __align__(16) bf16_t sB3[2][64 * BK];

  const int lane = threadIdx.x & 63, wave = threadIdx.x >> 6;
  const int wm = wave & 1, wn = wave >> 1;
  const int srr = lane >> 3;
  const int scol = ((lane & 7) ^ srr) * 8;   // swizzled gather column

  const bf16_t *aS[4], *b1S[2], *b3S[2];
#pragma unroll
  for (int i = 0; i < 4; ++i) {
    const int c = wave * 4 + i;              // A chunk 0..15 (8 rows each)
    const int r = c * 8 + srr;               // row 0..127
    aS[i] = xb + (size_t)list[slot0 + r] * DDIM + scol;
  }
#pragma unroll
  for (int i = 0; i < 2; ++i) {
    const int c = wave * 2 + i;              // B chunk 0..7
    const int r = c * 8 + srr;
    const size_t wb = (size_t)e * MATN + (size_t)(n0 + r) * DDIM + scol;
    b1S[i] = wt1 + wb; b3S[i] = wt3 + wb;
  }

  const f32x4 z = {0.f, 0.f, 0.f, 0.f};
  f32x4 aU[4][2], aV[4][2];
#pragma unroll
  for (int a = 0; a < 4; ++a)
#pragma unroll
    for (int b = 0; b < 2; ++b) { aU[a][b] = z; aV[a][b] = z; }

#define ISSUE12(j, b)                                            \
  _Pragma("unroll") for (int i = 0; i < 4; ++i)                  \
    load16(aS[i] + (j) * BK, &sA[b][(wave * 4 + i) * 512]);      \
  _Pragma("unroll") for (int i = 0; i < 2; ++i) {                \
    load16(b1S[i] + (j) * BK, &sB1[b][(wave * 2 + i) * 512]);    \
    load16(b3S[i] + (j) * BK, &sB3[b][(wave * 2 + i) * 512]);    \
  }

#define COMPUTE12(b)                                                          \
  _Pragma("unroll") for (int ks = 0; ks < 2; ++ks) {                          \
    const int kk = ks * 32 + ((lane >> 4) * 8);                               \
    bf16x8 af[4], f1[2], f3[2];                                               \
    _Pragma("unroll") for (int mf = 0; mf < 4; ++mf)                          \
      af[mf] = *(const bf16x8*)&sA[b][sw_off(wm * 64 + mf * 16 + (lane & 15), kk)]; \
    _Pragma("unroll") for (int nf = 0; nf < 2; ++nf) {                        \
      const int ro = sw_off(wn * 32 + nf * 16 + (lane & 15), kk);             \
      f1[nf] = *(const bf16x8*)&sB1[b][ro];                                   \
      f3[nf] = *(const bf16x8*)&sB3[b][ro];                                   \
    }                                                                         \
    _Pragma("unroll") for (int nf = 0; nf < 2; ++nf)                          \
      _Pragma("unroll") for (int mf = 0; mf < 4; ++mf) {                      \
        aU[mf][nf] = __builtin_amdgcn_mfma_f32_16x16x32_bf16(af[mf], f1[nf], aU[mf][nf], 0, 0, 0); \
        aV[mf][nf] = __builtin_amdgcn_mfma_f32_16x16x32_bf16(af[mf], f3[nf], aV[mf][nf], 0, 0, 0); \
      }                                                                       \
  }

  ISSUE12(0, 0);
#pragma unroll
  for (int j = 0; j < 15; ++j) {
    ISSUE12(j + 1, (j + 1) & 1);
    WVM(8); BAR();
    COMPUTE12(j & 1);
    BAR();
  }
  WVM(0); BAR();
  COMPUTE12(1);

  // epilogue: G = silu(U)*V.  C/D: col=lane&15, row=quad*4+reg (m89/m91)
  const int colb = n0 + wn * 32 + (lane & 15);
#pragma unroll
  for (int mf = 0; mf < 4; ++mf)
#pragma unroll
    for (int rg = 0; rg < 4; ++rg) {
      const int row = wm * 64 + mf * 16 + ((lane >> 4) * 4) + rg;
      bf16_t* gp = G + (size_t)(slot0 + row) * DDIM + colb;
#pragma unroll
      for (int nf = 0; nf < 2; ++nf) {
        const float u = aU[mf][nf][rg];
        gp[nf * 16] = (bf16_t)((u / (1.f + __expf(-u))) * aV[mf][nf][rg]);
      }
    }
#undef ISSUE12
#undef COMPUTE12
}

// ---------------- single-B GEMM (dbuf+swizzle, M=128). MODE: 0=U 1=V+SwiGLU 2=out ----------------
// LDS = 32+16 = 48 KB -> 3 blocks/CU.
template <int MODE>
__global__ __launch_bounds__(256, 3)
void gemmS_k(const bf16_t* __restrict__ Asrc, const bf16_t* __restrict__ wt,
             bf16_t* __restrict__ UG, float* __restrict__ oacc,
             const int* __restrict__ tile_e, const int* __restrict__ tile_m0,
             const int* __restrict__ ntp, const int* __restrict__ list,
             const float* __restrict__ wrow) {
  const int ti = blockIdx.y;
  if (ti >= ntp[0]) return;
  const int e = tile_e[ti], slot0 = tile_m0[ti];
  const int n0 = blockIdx.x * 64;

  __shared__ __align__(16) bf16_t sA[2][128 * BK];
  __shared__ __align__(16) bf16_t sB[2][64 * BK];

  const int lane = threadIdx.x & 63, wave = threadIdx.x >> 6;
  const int wm = wave & 1, wn = wave >> 1;
  const int srr = lane >> 3;
  const int scol = ((lane & 7) ^ srr) * 8;

  const bf16_t *aS[4], *bS[2];
#pragma unroll
  for (int i = 0; i < 4; ++i) {
    const int c = wave * 4 + i;
    const int r = c * 8 + srr;
    const int slot = slot0 + r;
    aS[i] = Asrc + (size_t)((MODE == 2) ? slot : list[slot]) * DDIM + scol;
  }
#pragma unroll
  for (int i = 0; i < 2; ++i) {
    const int c = wave * 2 + i;
    const int r = c * 8 + srr;
    bS[i] = wt + (size_t)e * MATN + (size_t)(n0 + r) * DDIM + scol;
  }

  const f32x4 z = {0.f, 0.f, 0.f, 0.f};
  f32x4 acc[4][2];
#pragma unroll
  for (int a = 0; a < 4; ++a)
#pragma unroll
    for (int b = 0; b < 2; ++b) acc[a][b] = z;

#define ISSUES(j, b)                                           \
  _Pragma("unroll") for (int i = 0; i < 4; ++i)                \
    load16(aS[i] + (j) * BK, &sA[b][(wave * 4 + i) * 512]);    \
  _Pragma("unroll") for (int i = 0; i < 2; ++i)                \
    load16(bS[i] + (j) * BK, &sB[b][(wave * 2 + i) * 512]);

#define COMPUTES(b)                                                           \
  _Pragma("unroll") for (int ks = 0; ks < 2; ++ks) {                          \
    const int kk = ks * 32 + ((lane >> 4) * 8);                               \
    bf16x8 af[4], fb[2];                                                      \
    _Pragma("unroll") for (int mf = 0; mf < 4; ++mf)                          \
      af[mf] = *(const bf16x8*)&sA[b][sw_off(wm * 64 + mf * 16 + (lane & 15), kk)]; \
    _Pragma("unroll") for (int nf = 0; nf < 2; ++nf)                          \
      fb[nf] = *(const bf16x8*)&sB[b][sw_off(wn * 32 + nf * 16 + (lane & 15), kk)]; \
    _Pragma("unroll") for (int nf = 0; nf < 2; ++nf)                          \
      _Pragma("unroll") for (int mf = 0; mf < 4; ++mf)                        \
        acc[mf][nf] = __builtin_amdgcn_mfma_f32_16x16x32_bf16(af[mf], fb[nf], acc[mf][nf], 0, 0, 0); \
  }

  ISSUES(0, 0);
#pragma unroll
  for (int j = 0; j < 15; ++j) {
    ISSUES(j + 1, (j + 1) & 1);
    WVM(6); BAR();
    COMPUTES(j & 1);
    BAR();
  }
  WVM(0); BAR();
  COMPUTES(1);

  const int colb = n0 + wn * 32 + (lane & 15);
#pragma unroll
  for (int mf = 0; mf < 4; ++mf)
#pragma unroll
    for (int rg = 0; rg < 4; ++rg) {
      const int row = wm * 64 + mf * 16 + ((lane >> 4) * 4) + rg;
      const int slot = slot0 + row;
      if (MODE == 0) {
        bf16_t* gp = UG + (size_t)slot * DDIM + colb;
#pragma unroll
        for (int nf = 0; nf < 2; ++nf) gp[nf * 16] = (bf16_t)acc[mf][nf][rg];
      } else if (MODE == 1) {
        bf16_t* gp = UG + (size_t)slot * DDIM + colb;
#pragma unroll
        for (int nf = 0; nf < 2; ++nf) {
          const float u = (float)gp[nf * 16];
          gp[nf * 16] = (bf16_t)((u / (1.f + __expf(-u))) * acc[mf][nf][rg]);
        }
      } else {
        const float w = wrow[slot];
        if (w != 0.f) {
          float* dst = oacc + (size_t)list[slot] * DDIM + colb;
#pragma unroll
          for (int nf = 0; nf < 2; ++nf)
            atomicAdd(dst + nf * 16, w * acc[mf][nf][rg]);
        }
      }
    }
#undef ISSUES
#undef COMPUTES
}

extern "C" void kernel_launch(void* const* d_in, const int* in_sizes, int n_in,
                              void* d_out, int out_size, void* d_ws, size_t ws_size,
                              hipStream_t stream) {
  (void)in_sizes; (void)n_in; (void)out_size;
  const float* x   = (const float*)d_in[0];
  const float* rw  = (const float*)d_in[1];
  const float* eb  = (const float*)d_in[2];
  const float* w1  = (const float*)d_in[3];
  const float* w2  = (const float*)d_in[4];
  const float* w3  = (const float*)d_in[5];
  const float* sw1 = (const float*)d_in[6];
  const float* sw2 = (const float*)d_in[7];
  const float* sw3 = (const float*)d_in[8];
  float* out = (float*)d_out;

  char* ws = (char*)d_ws;
  const size_t WT  = 18874368;   // 9 * 2 MiB bf16
  const size_t XBS = 2097152, GS = 8388608, MS = 65536;
  const int mode = (ws_size >= 3 * WT + XBS + GS + MS) ? 3
                 : (ws_size >= 2 * WT + XBS + GS + MS) ? 2 : 1;

  size_t off = 0;
  bf16_t* wtA = (bf16_t*)(ws); off += WT;
  bf16_t* wtB = wtA; bf16_t* wtC = wtA;
  if (mode >= 2) { wtB = (bf16_t*)(ws + off); off += WT; }
  if (mode == 3) { wtC = (bf16_t*)(ws + off); off += WT; }
  bf16_t* xb = (bf16_t*)(ws + off); off += XBS;
  bf16_t* G  = (bf16_t*)(ws + off); off += GS;
  int* meta  = (int*)(ws + off);

  int*   ntp     = meta + 32;
  int*   tile_e  = meta + 40;
  int*   tile_m0 = meta + 104;
  int*   tsel    = meta + 168;
  int*   list    = meta + 4264;
  float* tscore  = (float*)(meta + 8360);
  float* wrow    = (float*)(meta + 10408);

  prep_k<<<512, 256, 0, stream>>>(x, xb, out, list, wrow, rw, eb, tsel, tscore);

  if (mode == 3) {
    // all 27 transposes + pack in ONE dispatch (z slice 27 = pack block)
    transpose3_k<<<dim3(16, 16, 28), 256, 0, stream>>>(
        w1, sw1, wtA, w3, sw3, wtB, w2, sw2, wtC, 27,
        tsel, tscore, ntp, tile_e, tile_m0, list, wrow);
    gemm12_k<<<dim3(16, 31), 256, 0, stream>>>(xb, wtA, wtB, G, tile_e, tile_m0, ntp, list);
    gemmS_k<2><<<dim3(16, 31), 256, 0, stream>>>(G, wtC, G, out, tile_e, tile_m0, ntp, list, wrow);
  } else if (mode == 2) {
    transpose3_k<<<dim3(16, 16, 19), 256, 0, stream>>>(
        w1, sw1, wtA, w3, sw3, wtB, w3, sw3, wtB, 18,
        tsel, tscore, ntp, tile_e, tile_m0, list, wrow);
    gemm12_k<<<dim3(16, 31), 256, 0, stream>>>(xb, wtA, wtB, G, tile_e, tile_m0, ntp, list);
    transpose3_k<<<dim3(16, 16, 9), 256, 0, stream>>>(
        w2, sw2, wtA, w2, sw2, wtA, w2, sw2, wtA, 9,
        tsel, tscore, ntp, tile_e, tile_m0, list, wrow);
    gemmS_k<2><<<dim3(16, 31), 256, 0, stream>>>(G, wtA, G, out, tile_e, tile_m0, ntp, list, wrow);
  } else {
    transpose3_k<<<dim3(16, 16, 10), 256, 0, stream>>>(
        w1, sw1, wtA, w1, sw1, wtA, w1, sw1, wtA, 9,
        tsel, tscore, ntp, tile_e, tile_m0, list, wrow);
    gemmS_k<0><<<dim3(16, 31), 256, 0, stream>>>(xb, wtA, G, out, tile_e, tile_m0, ntp, list, wrow);
    transpose3_k<<<dim3(16, 16, 9), 256, 0, stream>>>(
        w3, sw3, wtA, w3, sw3, wtA, w3, sw3, wtA, 9,
        tsel, tscore, ntp, tile_e, tile_m0, list, wrow);
    gemmS_k<1><<<dim3(16, 31), 256, 0, stream>>>(xb, wtA, G, out, tile_e, tile_m0, ntp, list, wrow);
    transpose3_k<<<dim3(16, 16, 9), 256, 0, stream>>>(
        w2, sw2, wtA, w2, sw2, wtA, w2, sw2, wtA, 9,
        tsel, tscore, ntp, tile_e, tile_m0, list, wrow);
    gemmS_k<2><<<dim3(16, 31), 256, 0, stream>>>(G, wtA, G, out, tile_e, tile_m0, ntp, list, wrow);
  }
}